// Round 1
// baseline (31327.194 us; speedup 1.0000x reference)
//
#include <hip/hip_runtime.h>

// 2-layer GRU, I=8, H=128, T=32768 sequential steps, output = final h1 (128 f32).
// 3-role pipeline across CUs (layer1 never feeds layer0):
//   block 0          : layer-0 recurrence (w_hh0 in regs), publishes h0 stream
//   blocks 2..5      : "army" — gi1[t] = w_ih1 @ h0[t] + b_ih1 (parallel over t, mod-4)
//   block 1          : layer-1 recurrence (w_hh1 in regs), consumes gi1 stream
// Streams live in LLC-backed rings in d_ws, guarded by per-group (8-step)
// agent-scope acquire/release flags. Flags zeroed by hipMemsetAsync each call.

#define T_STEPS 32768
#define GS 8                   // steps per flag group
#define NG (T_STEPS / GS)      // 4096 groups
#define NARMY 4
#define HDIM 128
#define GDIM 384
#define SCOPE_AGENT __HIP_MEMORY_SCOPE_AGENT

__device__ __forceinline__ float sigm(float x) {
  return __fdividef(1.f, 1.f + __expf(-x));
}
__device__ __forceinline__ float tanh_fast(float x) {
  x = fminf(15.f, fmaxf(-15.f, x));
  float e = __expf(2.f * x);
  return (e - 1.f) * __fdividef(1.f, e + 1.f);
}
__device__ __forceinline__ float red4(float v) {
  v += __shfl_xor(v, 1);
  v += __shfl_xor(v, 2);
  return v;
}

// thread t: q = t&3 selects h-chunk [32q,32q+32); u = t>>2 selects row base.
// Owns rows u, u+128, u+256 (r/z/n gates of hidden unit u) x its quarter.
__device__ __forceinline__ void load_w(const float* __restrict__ W, int u, int q,
                                       float (&w)[3][32]) {
  #pragma unroll
  for (int m = 0; m < 3; ++m) {
    const float* src = W + (size_t)(u + 128 * m) * 128 + 32 * q;
    #pragma unroll
    for (int jj = 0; jj < 8; ++jj) {
      float4 v = *(const float4*)(src + 4 * jj);
      w[m][4 * jj + 0] = v.x; w[m][4 * jj + 1] = v.y;
      w[m][4 * jj + 2] = v.z; w[m][4 * jj + 3] = v.w;
    }
  }
}

__device__ __forceinline__ void dot3(const float (&w)[3][32], const float4 (&hv)[8],
                                     float& a0, float& a1, float& a2) {
  a0 = 0.f; a1 = 0.f; a2 = 0.f;
  #pragma unroll
  for (int jj = 0; jj < 8; ++jj) {
    const float hh[4] = {hv[jj].x, hv[jj].y, hv[jj].z, hv[jj].w};
    #pragma unroll
    for (int c = 0; c < 4; ++c) {
      a0 = fmaf(w[0][4 * jj + c], hh[c], a0);
      a1 = fmaf(w[1][4 * jj + c], hh[c], a1);
      a2 = fmaf(w[2][4 * jj + c], hh[c], a2);
    }
  }
  a0 = red4(a0); a1 = red4(a1); a2 = red4(a2);
}

__global__ __launch_bounds__(512, 2)
void unitrnn_pipe(const float* __restrict__ x,
                  const float* __restrict__ w_ih0, const float* __restrict__ w_hh0,
                  const float* __restrict__ b_ih0, const float* __restrict__ b_hh0,
                  const float* __restrict__ w_ih1, const float* __restrict__ w_hh1,
                  const float* __restrict__ b_ih1, const float* __restrict__ b_hh1,
                  float* __restrict__ out,
                  unsigned* flags_h0, unsigned* flags_gi1, unsigned* w1_prog,
                  float* h0_ring, float* gi1_ring, int ring_steps) {
  const int tid = threadIdx.x;
  const int q = tid & 3;
  const int u = tid >> 2;
  const int rmask = ring_steps - 1;
  const int ring_groups = ring_steps / GS;

  __shared__ __align__(16) float hbuf[2][HDIM];
  if (tid < HDIM) { hbuf[0][tid] = 0.f; hbuf[1][tid] = 0.f; }
  __syncthreads();

  const int bid = blockIdx.x;

  if (bid == 0) {
    // ======================= W0: layer-0 recurrence =======================
    float w[3][32];
    load_w(w_hh0, u, q, w);
    float wi[3][8];
    #pragma unroll
    for (int m = 0; m < 3; ++m) {
      #pragma unroll
      for (int i = 0; i < 8; ++i) wi[m][i] = w_ih0[(u + 128 * m) * 8 + i];
    }
    const float bsr = b_ih0[u] + b_hh0[u];
    const float bsz = b_ih0[u + 128] + b_hh0[u + 128];
    const float bin = b_ih0[u + 256];
    const float bhn = b_hh0[u + 256];

    int w1_seen = 0;
    for (int g = 0; g < NG; ++g) {
      while (g - w1_seen >= ring_groups) {  // ring back-pressure (rarely hit)
        w1_seen = (int)__hip_atomic_load(w1_prog, __ATOMIC_RELAXED, SCOPE_AGENT);
        __builtin_amdgcn_s_sleep(1);
      }
      #pragma unroll
      for (int s = 0; s < GS; ++s) {
        const int tstep = g * GS + s;
        const int pr = s & 1;  // g*GS is even, so parity == tstep&1
        float xv[8];
        #pragma unroll
        for (int i = 0; i < 8; ++i) xv[i] = x[(size_t)tstep * 8 + i];
        float4 hv[8];
        #pragma unroll
        for (int jj = 0; jj < 8; ++jj)
          hv[jj] = *(const float4*)&hbuf[pr][32 * q + 4 * jj];
        float a0, a1, a2;
        dot3(w, hv, a0, a1, a2);
        if (q == 0) {
          float gr = bsr, gz = bsz, gn = bin;
          #pragma unroll
          for (int i = 0; i < 8; ++i) {
            gr = fmaf(wi[0][i], xv[i], gr);
            gz = fmaf(wi[1][i], xv[i], gz);
            gn = fmaf(wi[2][i], xv[i], gn);
          }
          const float r = sigm(gr + a0);
          const float z = sigm(gz + a1);
          const float n = tanh_fast(gn + r * (a2 + bhn));
          const float hprev = hbuf[pr][u];
          const float hnew = (1.f - z) * n + z * hprev;
          hbuf[pr ^ 1][u] = hnew;
          h0_ring[(size_t)(tstep & rmask) * HDIM + u] = hnew;
        }
        __syncthreads();
      }
      __threadfence();   // make ring stores agent-visible
      __syncthreads();
      if (tid == 0)
        __hip_atomic_store(&flags_h0[g], 1u, __ATOMIC_RELEASE, SCOPE_AGENT);
    }
  } else if (bid == 1) {
    // ======================= W1: layer-1 recurrence =======================
    float w[3][32];
    load_w(w_hh1, u, q, w);
    const float bhr = b_hh1[u];
    const float bhz = b_hh1[u + 128];
    const float bhn1 = b_hh1[u + 256];

    for (int g = 0; g < NG; ++g) {
      while (__hip_atomic_load(&flags_gi1[g], __ATOMIC_ACQUIRE, SCOPE_AGENT) == 0u)
        __builtin_amdgcn_s_sleep(1);
      float gv[GS][3];
      if (q == 0) {
        #pragma unroll
        for (int s = 0; s < GS; ++s) {
          const float* src = gi1_ring + (size_t)((g * GS + s) & rmask) * GDIM + u;
          gv[s][0] = src[0]; gv[s][1] = src[128]; gv[s][2] = src[256];
        }
      }
      #pragma unroll
      for (int s = 0; s < GS; ++s) {
        const int pr = s & 1;
        float4 hv[8];
        #pragma unroll
        for (int jj = 0; jj < 8; ++jj)
          hv[jj] = *(const float4*)&hbuf[pr][32 * q + 4 * jj];
        float a0, a1, a2;
        dot3(w, hv, a0, a1, a2);
        if (q == 0) {
          const float r = sigm(gv[s][0] + a0 + bhr);
          const float z = sigm(gv[s][1] + a1 + bhz);
          const float n = tanh_fast(gv[s][2] + r * (a2 + bhn1));
          const float hprev = hbuf[pr][u];
          const float hnew = (1.f - z) * n + z * hprev;
          hbuf[pr ^ 1][u] = hnew;
          if (g == NG - 1 && s == GS - 1) out[u] = hnew;
        }
        __syncthreads();
      }
      if (tid == 0)
        __hip_atomic_store(w1_prog, (unsigned)(g + 1), __ATOMIC_RELAXED, SCOPE_AGENT);
    }
  } else {
    // ======================= army: gi1 = w_ih1 @ h0 + b_ih1 =======================
    const int a = bid - 2;
    float w[3][32];
    load_w(w_ih1, u, q, w);
    const float bir = b_ih1[u];
    const float biz = b_ih1[u + 128];
    const float bin1 = b_ih1[u + 256];

    int w1_seen = 0;
    for (int g = a; g < NG; g += NARMY) {
      while (g - w1_seen >= ring_groups) {  // don't overwrite unconsumed gi1
        w1_seen = (int)__hip_atomic_load(w1_prog, __ATOMIC_RELAXED, SCOPE_AGENT);
        __builtin_amdgcn_s_sleep(1);
      }
      while (__hip_atomic_load(&flags_h0[g], __ATOMIC_ACQUIRE, SCOPE_AGENT) == 0u)
        __builtin_amdgcn_s_sleep(1);
      #pragma unroll
      for (int s = 0; s < GS; ++s) {
        const int tstep = g * GS + s;
        const float* hsrc = h0_ring + (size_t)(tstep & rmask) * HDIM + 32 * q;
        float4 hv[8];
        #pragma unroll
        for (int jj = 0; jj < 8; ++jj)
          hv[jj] = *(const float4*)(hsrc + 4 * jj);
        float a0, a1, a2;
        dot3(w, hv, a0, a1, a2);
        if (q == 0) {
          float* dst = gi1_ring + (size_t)(tstep & rmask) * GDIM + u;
          dst[0]   = a0 + bir;
          dst[128] = a1 + biz;
          dst[256] = a2 + bin1;
        }
      }
      __threadfence();
      __syncthreads();
      if (tid == 0)
        __hip_atomic_store(&flags_gi1[g], 1u, __ATOMIC_RELEASE, SCOPE_AGENT);
    }
  }
}

extern "C" void kernel_launch(void* const* d_in, const int* in_sizes, int n_in,
                              void* d_out, int out_size, void* d_ws, size_t ws_size,
                              hipStream_t stream) {
  (void)in_sizes; (void)n_in; (void)out_size;
  const float* x     = (const float*)d_in[0];
  const float* w_ih0 = (const float*)d_in[1];
  const float* w_hh0 = (const float*)d_in[2];
  const float* b_ih0 = (const float*)d_in[3];
  const float* b_hh0 = (const float*)d_in[4];
  const float* w_ih1 = (const float*)d_in[5];
  const float* w_hh1 = (const float*)d_in[6];
  const float* b_ih1 = (const float*)d_in[7];
  const float* b_hh1 = (const float*)d_in[8];
  float* out = (float*)d_out;

  const size_t flags_bytes = (size_t)2 * NG * sizeof(unsigned) + 256;  // 16B-aligned
  int ring_steps = 1024;  // adapt to ws_size; lag is only ~tens of steps
  while (ring_steps > 16 &&
         flags_bytes + (size_t)ring_steps * (HDIM + GDIM) * sizeof(float) > ws_size)
    ring_steps >>= 1;

  unsigned* flags_h0  = (unsigned*)d_ws;
  unsigned* flags_gi1 = flags_h0 + NG;
  unsigned* w1_prog   = flags_gi1 + NG;
  float* h0_ring  = (float*)((char*)d_ws + flags_bytes);
  float* gi1_ring = h0_ring + (size_t)ring_steps * HDIM;

  hipMemsetAsync(d_ws, 0, flags_bytes, stream);
  hipLaunchKernelGGL(unitrnn_pipe, dim3(2 + NARMY), dim3(512), 0, stream,
                     x, w_ih0, w_hh0, b_ih0, b_hh0,
                     w_ih1, w_hh1, b_ih1, b_hh1, out,
                     flags_h0, flags_gi1, w1_prog, h0_ring, gi1_ring, ring_steps);
}